// Round 9
// baseline (14946.245 us; speedup 1.0000x reference)
//
#include <hip/hip_runtime.h>
#include <hip/hip_fp16.h>
#include <math.h>

// ---------------- constants ----------------
#define T_STEPS 8192
#define IN_DIM  1024
#define HD      1024
#define ZD      4096          // 4 gates * HD, order [i, j, f, o]
#define G2      64            // phase-2 workgroups (each owns 16 h-cols x 4 gates)
#define B2      512           // phase-2 block size (8 waves)

typedef short  short8 __attribute__((ext_vector_type(8)));
typedef float  f32x4  __attribute__((ext_vector_type(4)));
typedef unsigned uint4v __attribute__((ext_vector_type(4)));
typedef _Float16 h2v __attribute__((ext_vector_type(2)));

__device__ __forceinline__ unsigned short f2bf(float f) {
    unsigned u = __float_as_uint(f);
    unsigned r = (u + 0x7fffu + ((u >> 16) & 1u)) >> 16;
    return (unsigned short)r;
}

// pack 2 fp32 -> 2 fp16 (RTZ) as a dword; bit_cast bridges __fp16 vs _Float16 types
__device__ __forceinline__ unsigned pk16(float a, float b) {
    return __builtin_bit_cast(unsigned, __builtin_amdgcn_cvt_pkrtz(a, b));
}

// ---------------- phase 0: pack Wx (rows 0..1023 of W) into bf16 tile layout ----
__global__ void wt_pack(const float* __restrict__ W, unsigned short* __restrict__ Wt) {
    int idx = blockIdx.x * 256 + threadIdx.x;      // 0 .. 4M-1
    int k = idx >> 12;                             // 0..1023
    int c = idx & 4095;                            // 0..4095
    float v = W[(size_t)k * ZD + c];               // coalesced read
    int tn = c >> 7, col = c & 127;
    int tk = k >> 5, kk = k & 31;
    Wt[(((size_t)(tn * 32 + tk) * 128 + col) << 5) + kk] = f2bf(v);
}

// ---------------- phase 0b: pack Wh (rows 1024..2047) into fp16 per-thread runs --
__global__ void whp_pack(const float* __restrict__ W, unsigned* __restrict__ Whp) {
    int i = blockIdx.x * 256 + threadIdx.x;   // 0..32767
    int zcol = i & 4095;
    int seg  = i >> 12;                       // 0..7
    const float* src = W + (size_t)(IN_DIM + (seg << 7)) * ZD + zcol; // lane-coalesced
    unsigned* dst = Whp + ((size_t)zcol * 8 + seg) * 64;              // 256B/thread
    for (int j = 0; j < 64; ++j) {
        float v0 = src[(size_t)(2 * j) * ZD];
        float v1 = src[(size_t)(2 * j + 1) * ZD];
        unsigned lo = (unsigned)__half_as_ushort(__float2half(v0));
        unsigned hi = (unsigned)__half_as_ushort(__float2half(v1));
        dst[j] = lo | (hi << 16);
    }
}

// ---------------- phase 1: ZX = x @ Wx + b (bf16 MFMA, fp32 accum) --------------
#define BM 128
#define BN 128
#define BKK 32
#define LDA 40    // padded LDS stride (bf16 elems)

__global__ __launch_bounds__(256) void zx_gemm(const float* __restrict__ x,
                                               const unsigned short* __restrict__ Wt,
                                               const float* __restrict__ b,
                                               float* __restrict__ zx) {
    __shared__ unsigned short As[128 * LDA];
    __shared__ unsigned short Bs[128 * LDA];
    const int tid  = threadIdx.x;
    const int wave = tid >> 6, lane = tid & 63;
    const int wr = wave & 1, wc = wave >> 1;
    const int m0 = blockIdx.y * BM, n0 = blockIdx.x * BN;
    const int quad = lane >> 4, l16 = lane & 15;

    f32x4 acc[4][4] = {};
    float bias[4];
#pragma unroll
    for (int j = 0; j < 4; ++j) bias[j] = b[n0 + wc * 64 + j * 16 + l16];

    for (int it = 0; it < IN_DIM / BKK; ++it) {
        const int k0 = it * BKK;
        // stage A: x[m0..+127][k0..+31] fp32 -> bf16 LDS
        {
            int r  = tid >> 3;          // 0..31
            int k4 = (tid & 7) * 4;
#pragma unroll
            for (int p = 0; p < 4; ++p) {
                int rr = r + p * 32;
                float4 v = *(const float4*)&x[(size_t)(m0 + rr) * IN_DIM + k0 + k4];
                unsigned p0 = (unsigned)f2bf(v.x) | ((unsigned)f2bf(v.y) << 16);
                unsigned p1 = (unsigned)f2bf(v.z) | ((unsigned)f2bf(v.w) << 16);
                *(uint2*)&As[rr * LDA + k4] = make_uint2(p0, p1);
            }
        }
        // stage B: pre-packed contiguous 8KB tile -> LDS (pad stride 40)
        {
            const uint4* src = (const uint4*)(Wt + ((size_t)(n0 >> 7) * 32 + it) * 4096);
#pragma unroll
            for (int p = 0; p < 2; ++p) {
                int id = tid * 2 + p;           // 0..511
                int col = id >> 2, kp = id & 3;
                uint4 v = src[id];
                *(uint4*)&Bs[col * LDA + kp * 8] = v;
            }
        }
        __syncthreads();
        short8 af[4], bfr[4];
#pragma unroll
        for (int i = 0; i < 4; ++i)
            af[i] = *(const short8*)&As[(wr * 64 + i * 16 + l16) * LDA + quad * 8];
#pragma unroll
        for (int j = 0; j < 4; ++j)
            bfr[j] = *(const short8*)&Bs[(wc * 64 + j * 16 + l16) * LDA + quad * 8];
#pragma unroll
        for (int i = 0; i < 4; ++i)
#pragma unroll
            for (int j = 0; j < 4; ++j)
                acc[i][j] = __builtin_amdgcn_mfma_f32_16x16x32_bf16(af[i], bfr[j], acc[i][j], 0, 0, 0);
        __syncthreads();
    }
    // epilogue: D row = quad*4 + reg, col = l16
#pragma unroll
    for (int i = 0; i < 4; ++i) {
        int row = m0 + wr * 64 + i * 16 + quad * 4;
#pragma unroll
        for (int j = 0; j < 4; ++j) {
            int col = n0 + wc * 64 + j * 16 + l16;
#pragma unroll
            for (int r = 0; r < 4; ++r)
                zx[(size_t)(row + r) * ZD + col] = acc[i][j][r] + bias[j];
        }
    }
}

// ---------------- fast activations (critical path) ----------------
__device__ __forceinline__ float sigmoid_fast(float x) {
    float e = __expf(-x);
    return __builtin_amdgcn_rcpf(1.f + e);
}
__device__ __forceinline__ float tanh_fast(float x) {
    // 1 - 2/(e^{2x}+1); e=inf -> 1, e=0 -> -1 (no NaN at extremes)
    float e = __expf(2.f * x);
    return 1.f - 2.f * __builtin_amdgcn_rcpf(e + 1.f);
}

// ---------------- phase 2: sequential recurrence (cooperative, 64 WGs) ----------
// Base = round-5 PASSING structure (11.96ms). r8's XCD-local sc0 path was unsound
// (dirty hslot lines in other XCDs' write-back L2s from the ws poison can clobber
// tags; profiled run showed 1.43s pathological spins) -> GLOBAL protocol only.
// Change vs r5 (targets the proven lever: r4->r5 poll-request halving = -0.44us/step):
//  * h packets are 2B bf16 whose mantissa LSB carries ONE tag bit. A 16B chunk =
//    8 bf16 = an 8-bit distributed tag. Per-ELEMENT tags keep the r5 soundness
//    property: partial store visibility is a retry, never a hazard; no ordering
//    or atomicity requirements.
//  * wave slice 128 h = 256B -> 16 poll lanes/wave (was 32). Total poll requests
//    16384 -> 8192, hot LLC lines 64 -> 32.
//  * spin check: hoisted XOR masks, 8 in-loop ops; detect -> 8 bf16 -> 4 fp16-pair
//    dwords (~20 VALU, off-spin) -> same dot2 path as r5.
//  * h precision 24-bit -> 7-bit-mantissa bf16 (rel err <=2^-8, comparable to the
//    bf16 GEMM path). Expected absmax ~0.006-0.011 vs threshold 0.0165.
// Hazard audit identical to r5 (pbuf parity dbuf, zx_lds parity, own-wave lds_hh).
__global__ __launch_bounds__(B2, 2) void lstm_seq(const unsigned* __restrict__ whp,
                                                  const float* __restrict__ zx,
                                                  float* __restrict__ out,
                                                  unsigned short* hslot) {
    __shared__ unsigned lds_hh[512];       // fp16-packed h: dword d = {h[2d], h[2d+1]}
    __shared__ float pbuf[2][B2];
    __shared__ float zx_lds[2][64];
    const int g    = blockIdx.x;
    const int t    = threadIdx.x;
    const int seg  = t >> 6;           // 0..7 == wave index
    const int lane = t & 63;
    const int gate = lane >> 4;        // 0..3  [i,j,f,o]
    const int cidx = lane & 15;
    const int zcol = g * 16 + cidx + (gate << 10);

    // Wh slice -> 64 packed-fp16 dwords (compiler-managed; pinning proved harmful)
    unsigned wp[64];
    {
        const unsigned* wsrc = whp + ((size_t)zcol * 8 + seg) * 64;
#pragma unroll
        for (int j = 0; j < 64; ++j) wp[j] = wsrc[j];
    }

    // preload zx row 0 (wave 1); consumed in phase C of step 0
    if (t >= 64 && t < 128) {
        int l = t - 64;
        zx_lds[0][l] = zx[(size_t)0 * ZD + (size_t)(l >> 4) * 1024 + g * 16 + (l & 15)];
    }
    __syncthreads();   // cover zx_lds[0] for step-0 C-phase (outside the loop)

    float c_state = 0.f;

    for (int s = 0; s < T_STEPS; ++s) {
        const int par = s & 1;
        // wave 1: issue zx prefetch for step s+1 BEFORE the spin (overlaps the
        // poll's vmcnt(0) wait — max, not sum; r7 proved moving it later hurts)
        float znext = 0.f;
        if (t >= 64 && t < 128 && s + 1 < T_STEPS) {
            int l = t - 64;
            znext = zx[(size_t)(s + 1) * ZD + (size_t)(l >> 4) * 1024 + g * 16 + (l & 15)];
        }
        // ---- A: acquire own slice — 16 lanes poll 16B = 8 bf16, tag bit in each
        // element's mantissa LSB (elem k of a chunk carries bit k of the tag) ----
        if (lane < 16) {
            const unsigned want = (unsigned)(s & 255);
            const unsigned exp0 = ((want >> 0) & 1) | (((want >> 1) & 1) << 16);
            const unsigned exp1 = ((want >> 2) & 1) | (((want >> 3) & 1) << 16);
            const unsigned exp2 = ((want >> 4) & 1) | (((want >> 5) & 1) << 16);
            const unsigned exp3 = ((want >> 6) & 1) | (((want >> 7) & 1) << 16);
            const unsigned short* ap = hslot + (par << 10) + (seg << 7) + (lane << 3);
            uint4v pv;
            for (;;) {
                asm volatile("global_load_dwordx4 %0, %1, off sc0 sc1\n\t"
                             "s_waitcnt vmcnt(0)"
                             : "=v"(pv) : "v"(ap) : "memory");
                unsigned bad = ((pv.x ^ exp0) | (pv.y ^ exp1) |
                                (pv.z ^ exp2) | (pv.w ^ exp3)) & 0x00010001u;
                if (bad == 0) break;
            }
            // 8 bf16 (LSB = tag bit, mask it) -> 4 fp16-pair dwords for dot2
            unsigned d0 = pk16(__uint_as_float((pv.x & 0x0000FFFEu) << 16),
                               __uint_as_float(pv.x & 0xFFFE0000u));
            unsigned d1 = pk16(__uint_as_float((pv.y & 0x0000FFFEu) << 16),
                               __uint_as_float(pv.y & 0xFFFE0000u));
            unsigned d2 = pk16(__uint_as_float((pv.z & 0x0000FFFEu) << 16),
                               __uint_as_float(pv.z & 0xFFFE0000u));
            unsigned d3 = pk16(__uint_as_float((pv.w & 0x0000FFFEu) << 16),
                               __uint_as_float(pv.w & 0xFFFE0000u));
            *(uint4*)&lds_hh[(seg << 6) + (lane << 2)] = make_uint4(d0, d1, d2, d3);
        }
        // ---- B: 64 dot2 against fp16 weights (own slice) ----
        float a0 = 0.f, a1 = 0.f, a2 = 0.f, a3 = 0.f;
        const uint4* hp = (const uint4*)&lds_hh[seg << 6];
#pragma unroll
        for (int j = 0; j < 16; ++j) {
            uint4 hv = hp[j];    // same addr across wave: LDS broadcast, no conflict
            a0 = __builtin_amdgcn_fdot2(__builtin_bit_cast(h2v, wp[4 * j + 0]),
                                        __builtin_bit_cast(h2v, hv.x), a0, false);
            a1 = __builtin_amdgcn_fdot2(__builtin_bit_cast(h2v, wp[4 * j + 1]),
                                        __builtin_bit_cast(h2v, hv.y), a1, false);
            a2 = __builtin_amdgcn_fdot2(__builtin_bit_cast(h2v, wp[4 * j + 2]),
                                        __builtin_bit_cast(h2v, hv.z), a2, false);
            a3 = __builtin_amdgcn_fdot2(__builtin_bit_cast(h2v, wp[4 * j + 3]),
                                        __builtin_bit_cast(h2v, hv.w), a3, false);
        }
        pbuf[par][t] = (a0 + a1) + (a2 + a3);
        if (t >= 64 && t < 128)                  // park prefetched zx for next step
            zx_lds[(s + 1) & 1][t - 64] = znext;
        __syncthreads();                         // the ONLY barrier per step
        // ---- C: wave 0 reduces, gates, publishes ----
        if (t < 64) {
            float z = zx_lds[s & 1][t];
#pragma unroll
            for (int ss = 0; ss < 8; ++ss) z += pbuf[par][(ss << 6) + t];
            float zi = __shfl(z, cidx);
            float zj = __shfl(z, 16 + cidx);
            float zf = __shfl(z, 32 + cidx);
            float zo = __shfl(z, 48 + cidx);
            if (t < 16) {
                float fg = sigmoid_fast(zf + 1.0f);   // FORGET_BIAS = 1.0
                float ig = sigmoid_fast(zi);
                float og = sigmoid_fast(zo);
                c_state = c_state * fg + ig * tanh_fast(zj);
                float h = tanh_fast(c_state) * og;
                // publish: bf16 h, mantissa LSB = tag bit (t&7) of (s+1)&255;
                // 16 device-scope 2B stores per WG (one 32B region)
                unsigned hb = (unsigned)f2bf(h);
                unsigned short pkt = (unsigned short)
                    ((hb & 0xFFFEu) | (((unsigned)(s + 1) >> (t & 7)) & 1u));
                __hip_atomic_store(&hslot[(((s + 1) & 1) << 10) + g * 16 + t], pkt,
                                   __ATOMIC_RELAXED, __HIP_MEMORY_SCOPE_AGENT);
                out[(size_t)s * HD + g * 16 + t] = h;  // off critical path
            }
        }
    }
}

// ---------------- launch ----------------
extern "C" void kernel_launch(void* const* d_in, const int* in_sizes, int n_in,
                              void* d_out, int out_size, void* d_ws, size_t ws_size,
                              hipStream_t stream) {
    const float* x = (const float*)d_in[0];   // [8192,1024]
    const float* W = (const float*)d_in[1];   // [2048,4096]
    const float* b = (const float*)d_in[2];   // [4096]
    float* out = (float*)d_out;               // [8192,1024]

    char* ws = (char*)d_ws;
    // ws layout: zx 128MB | hslot 16KB region (4KB used) | Wt/Whp 8MB (time-shared)
    float*          zxp   = (float*)ws;
    const size_t    ZXB   = (size_t)T_STEPS * ZD * sizeof(float);   // 134217728
    unsigned short* hslot = (unsigned short*)(ws + ZXB);
    unsigned short* Wt    = (unsigned short*)(ws + ZXB + 16384);
    unsigned*       Whp   = (unsigned*)(ws + ZXB + 16384);          // reuses Wt region

    // h_0 = 0 with all tag bits 0 (= tag 0) in both parity slots
    hipMemsetAsync(hslot, 0, 4096, stream);

    // phase 0: pack Wx -> bf16 tiles
    wt_pack<<<dim3((IN_DIM * ZD) / 256), dim3(256), 0, stream>>>(W, Wt);

    // phase 1: ZX = x @ Wx + b
    zx_gemm<<<dim3(ZD / BN, T_STEPS / BM), dim3(256), 0, stream>>>(x, Wt, b, zxp);

    // phase 0b: pack Wh -> fp16 pairs into the now-dead Wt region (stream-ordered)
    whp_pack<<<dim3(128), dim3(256), 0, stream>>>(W, Whp);

    // phase 2: sequential recurrence (cooperative for guaranteed co-residency)
    void* args[] = { (void*)&Whp, (void*)&zxp, (void*)&out, (void*)&hslot };
    hipLaunchCooperativeKernel((void*)lstm_seq, dim3(G2), dim3(B2), args, 0, stream);
}

// Round 10
// 12680.338 us; speedup vs baseline: 1.1787x; 1.1787x over previous
//
#include <hip/hip_runtime.h>
#include <hip/hip_fp16.h>
#include <math.h>

// ---------------- constants ----------------
#define T_STEPS 8192
#define IN_DIM  1024
#define HD      1024
#define ZD      4096          // 4 gates * HD, order [i, j, f, o]
#define G2      64            // phase-2 workgroups (each owns 16 h-cols x 4 gates)
#define B2      512           // phase-2 block size (8 waves)

typedef short  short8 __attribute__((ext_vector_type(8)));
typedef float  f32x4  __attribute__((ext_vector_type(4)));
typedef unsigned uint4v __attribute__((ext_vector_type(4)));
typedef _Float16 h2v __attribute__((ext_vector_type(2)));

__device__ __forceinline__ unsigned short f2bf(float f) {
    unsigned u = __float_as_uint(f);
    unsigned r = (u + 0x7fffu + ((u >> 16) & 1u)) >> 16;
    return (unsigned short)r;
}

// pack 2 fp32 -> 2 fp16 (RTZ) as a dword; bit_cast bridges __fp16 vs _Float16 types
__device__ __forceinline__ unsigned pk16(float a, float b) {
    return __builtin_bit_cast(unsigned, __builtin_amdgcn_cvt_pkrtz(a, b));
}

// ---------------- phase 0: pack Wx (rows 0..1023 of W) into bf16 tile layout ----
__global__ void wt_pack(const float* __restrict__ W, unsigned short* __restrict__ Wt) {
    int idx = blockIdx.x * 256 + threadIdx.x;      // 0 .. 4M-1
    int k = idx >> 12;                             // 0..1023
    int c = idx & 4095;                            // 0..4095
    float v = W[(size_t)k * ZD + c];               // coalesced read
    int tn = c >> 7, col = c & 127;
    int tk = k >> 5, kk = k & 31;
    Wt[(((size_t)(tn * 32 + tk) * 128 + col) << 5) + kk] = f2bf(v);
}

// ---------------- phase 0b: pack Wh (rows 1024..2047) into fp16 per-thread runs --
__global__ void whp_pack(const float* __restrict__ W, unsigned* __restrict__ Whp) {
    int i = blockIdx.x * 256 + threadIdx.x;   // 0..32767
    int zcol = i & 4095;
    int seg  = i >> 12;                       // 0..7
    const float* src = W + (size_t)(IN_DIM + (seg << 7)) * ZD + zcol; // lane-coalesced
    unsigned* dst = Whp + ((size_t)zcol * 8 + seg) * 64;              // 256B/thread
    for (int j = 0; j < 64; ++j) {
        float v0 = src[(size_t)(2 * j) * ZD];
        float v1 = src[(size_t)(2 * j + 1) * ZD];
        unsigned lo = (unsigned)__half_as_ushort(__float2half(v0));
        unsigned hi = (unsigned)__half_as_ushort(__float2half(v1));
        dst[j] = lo | (hi << 16);
    }
}

// ---------------- phase 1: ZX = x @ Wx + b (bf16 MFMA, fp32 accum) --------------
#define BM 128
#define BN 128
#define BKK 32
#define LDA 40    // padded LDS stride (bf16 elems)

__global__ __launch_bounds__(256) void zx_gemm(const float* __restrict__ x,
                                               const unsigned short* __restrict__ Wt,
                                               const float* __restrict__ b,
                                               float* __restrict__ zx) {
    __shared__ unsigned short As[128 * LDA];
    __shared__ unsigned short Bs[128 * LDA];
    const int tid  = threadIdx.x;
    const int wave = tid >> 6, lane = tid & 63;
    const int wr = wave & 1, wc = wave >> 1;
    const int m0 = blockIdx.y * BM, n0 = blockIdx.x * BN;
    const int quad = lane >> 4, l16 = lane & 15;

    f32x4 acc[4][4] = {};
    float bias[4];
#pragma unroll
    for (int j = 0; j < 4; ++j) bias[j] = b[n0 + wc * 64 + j * 16 + l16];

    for (int it = 0; it < IN_DIM / BKK; ++it) {
        const int k0 = it * BKK;
        // stage A: x[m0..+127][k0..+31] fp32 -> bf16 LDS
        {
            int r  = tid >> 3;          // 0..31
            int k4 = (tid & 7) * 4;
#pragma unroll
            for (int p = 0; p < 4; ++p) {
                int rr = r + p * 32;
                float4 v = *(const float4*)&x[(size_t)(m0 + rr) * IN_DIM + k0 + k4];
                unsigned p0 = (unsigned)f2bf(v.x) | ((unsigned)f2bf(v.y) << 16);
                unsigned p1 = (unsigned)f2bf(v.z) | ((unsigned)f2bf(v.w) << 16);
                *(uint2*)&As[rr * LDA + k4] = make_uint2(p0, p1);
            }
        }
        // stage B: pre-packed contiguous 8KB tile -> LDS (pad stride 40)
        {
            const uint4* src = (const uint4*)(Wt + ((size_t)(n0 >> 7) * 32 + it) * 4096);
#pragma unroll
            for (int p = 0; p < 2; ++p) {
                int id = tid * 2 + p;           // 0..511
                int col = id >> 2, kp = id & 3;
                uint4 v = src[id];
                *(uint4*)&Bs[col * LDA + kp * 8] = v;
            }
        }
        __syncthreads();
        short8 af[4], bfr[4];
#pragma unroll
        for (int i = 0; i < 4; ++i)
            af[i] = *(const short8*)&As[(wr * 64 + i * 16 + l16) * LDA + quad * 8];
#pragma unroll
        for (int j = 0; j < 4; ++j)
            bfr[j] = *(const short8*)&Bs[(wc * 64 + j * 16 + l16) * LDA + quad * 8];
#pragma unroll
        for (int i = 0; i < 4; ++i)
#pragma unroll
            for (int j = 0; j < 4; ++j)
                acc[i][j] = __builtin_amdgcn_mfma_f32_16x16x32_bf16(af[i], bfr[j], acc[i][j], 0, 0, 0);
        __syncthreads();
    }
    // epilogue: D row = quad*4 + reg, col = l16
#pragma unroll
    for (int i = 0; i < 4; ++i) {
        int row = m0 + wr * 64 + i * 16 + quad * 4;
#pragma unroll
        for (int j = 0; j < 4; ++j) {
            int col = n0 + wc * 64 + j * 16 + l16;
#pragma unroll
            for (int r = 0; r < 4; ++r)
                zx[(size_t)(row + r) * ZD + col] = acc[i][j][r] + bias[j];
        }
    }
}

// ---------------- fast activations (critical path) ----------------
__device__ __forceinline__ float sigmoid_fast(float x) {
    float e = __expf(-x);
    return __builtin_amdgcn_rcpf(1.f + e);
}
__device__ __forceinline__ float tanh_fast(float x) {
    // 1 - 2/(e^{2x}+1); e=inf -> 1, e=0 -> -1 (no NaN at extremes)
    float e = __expf(2.f * x);
    return 1.f - 2.f * __builtin_amdgcn_rcpf(e + 1.f);
}

// ---------------- phase 2: sequential recurrence (cooperative, 64 WGs) ----------
// Base = round-5 PASSING kernel (11.96ms, best verified). ONE change:
// PIN the 64 packed-fp16 weight dwords in VGPRs. Why this matters NOW:
//  * r5's VGPR_Count=56 proves wp[] was rematerialized; the spin asm's "memory"
//    clobber forces those 64 loads (256B/thread = 128KB/CU from L2) to re-issue
//    AFTER the spin completes -> ~800-1300cy of L2 weight streaming sits serially
//    on the post-detect critical path, every step. Pinning removes it.
//  * r1's pin failed because 128 fp32 VGPRs overflowed the launch_bounds(512,2)
//    cap of 128; here it's 64 dwords under a (512,1) cap of 256 (~120 total used).
//    (512,1) costs nothing: only 1 WG/CU is resident anyway (64 WGs / 256 CUs).
//  * r9's bf16-packet regression (14.7ms despite -80MB FETCH) showed poll VOLUME
//    isn't the lever; publish latency + post-detect work is. This targets the
//    latter. Protocol reverted to r5 byte-for-byte (4B packets, 32 poll lanes).
__global__ __launch_bounds__(B2, 1) void lstm_seq(const unsigned* __restrict__ whp,
                                                  const float* __restrict__ zx,
                                                  float* __restrict__ out,
                                                  unsigned* hslot) {
    __shared__ unsigned lds_hh[512];       // fp16-packed h: dword d = {h[2d], h[2d+1]}
    __shared__ float pbuf[2][B2];
    __shared__ float zx_lds[2][64];
    const int g    = blockIdx.x;
    const int t    = threadIdx.x;
    const int seg  = t >> 6;           // 0..7 == wave index
    const int lane = t & 63;
    const int gate = lane >> 4;        // 0..3  [i,j,f,o]
    const int cidx = lane & 15;
    const int zcol = g * 16 + cidx + (gate << 10);

    // ---- Wh slice -> 64 packed-fp16 dwords, PINNED in VGPRs (see header) ----
    unsigned wp[64];
    {
        const unsigned* wsrc = whp + ((size_t)zcol * 8 + seg) * 64;
#pragma unroll
        for (int j = 0; j < 64; ++j) wp[j] = wsrc[j];
    }
#pragma unroll
    for (int j = 0; j < 64; ++j) asm volatile("" : "+v"(wp[j]));

    // preload zx row 0 (wave 1); consumed in phase C of step 0
    if (t >= 64 && t < 128) {
        int l = t - 64;
        zx_lds[0][l] = zx[(size_t)0 * ZD + (size_t)(l >> 4) * 1024 + g * 16 + (l & 15)];
    }
    __syncthreads();   // cover zx_lds[0] for step-0 C-phase (outside the loop)

    float c_state = 0.f;

    for (int s = 0; s < T_STEPS; ++s) {
        const int par = s & 1;
        // wave 1: issue zx prefetch for step s+1 BEFORE the spin (overlaps the
        // poll's vmcnt(0) wait — max, not sum; r7 proved moving it later hurts)
        float znext = 0.f;
        if (t >= 64 && t < 128 && s + 1 < T_STEPS) {
            int l = t - 64;
            znext = zx[(size_t)(s + 1) * ZD + (size_t)(l >> 4) * 1024 + g * 16 + (l & 15)];
        }
        // ---- A: acquire own slice — lanes 0..31 poll 16B = 4 tagged packets ----
        if (lane < 32) {
            const unsigned want = (unsigned)(s & 255);
            const unsigned* ap = hslot + (par << 10) + (seg << 7) + (lane << 2);
            uint4v pv;
            for (;;) {
                asm volatile("global_load_dwordx4 %0, %1, off sc0 sc1\n\t"
                             "s_waitcnt vmcnt(0)"
                             : "=v"(pv) : "v"(ap) : "memory");
                unsigned bad = ((pv.x ^ want) | (pv.y ^ want) |
                                (pv.z ^ want) | (pv.w ^ want)) & 255u;
                if (bad == 0) break;
            }
            // convert 4 fp32 packets -> 2 packed-fp16 dwords (tag bits sub-ulp)
            unsigned d0 = pk16(__uint_as_float(pv.x), __uint_as_float(pv.y));
            unsigned d1 = pk16(__uint_as_float(pv.z), __uint_as_float(pv.w));
            *(uint2*)&lds_hh[(seg << 6) + 2 * lane] = make_uint2(d0, d1);
        }
        // ---- B: 64 dot2 against register-resident fp16 weights (own slice) ----
        float a0 = 0.f, a1 = 0.f, a2 = 0.f, a3 = 0.f;
        const uint4* hp = (const uint4*)&lds_hh[seg << 6];
#pragma unroll
        for (int j = 0; j < 16; ++j) {
            uint4 hv = hp[j];    // same addr across wave: LDS broadcast, no conflict
            a0 = __builtin_amdgcn_fdot2(__builtin_bit_cast(h2v, wp[4 * j + 0]),
                                        __builtin_bit_cast(h2v, hv.x), a0, false);
            a1 = __builtin_amdgcn_fdot2(__builtin_bit_cast(h2v, wp[4 * j + 1]),
                                        __builtin_bit_cast(h2v, hv.y), a1, false);
            a2 = __builtin_amdgcn_fdot2(__builtin_bit_cast(h2v, wp[4 * j + 2]),
                                        __builtin_bit_cast(h2v, hv.z), a2, false);
            a3 = __builtin_amdgcn_fdot2(__builtin_bit_cast(h2v, wp[4 * j + 3]),
                                        __builtin_bit_cast(h2v, hv.w), a3, false);
        }
        pbuf[par][t] = (a0 + a1) + (a2 + a3);
        if (t >= 64 && t < 128)                  // park prefetched zx for next step
            zx_lds[(s + 1) & 1][t - 64] = znext;
        __syncthreads();                         // the ONLY barrier per step
        // ---- C: wave 0 reduces, gates, publishes ----
        if (t < 64) {
            float z = zx_lds[s & 1][t];
#pragma unroll
            for (int ss = 0; ss < 8; ++ss) z += pbuf[par][(ss << 6) + t];
            float zi = __shfl(z, cidx);
            float zj = __shfl(z, 16 + cidx);
            float zf = __shfl(z, 32 + cidx);
            float zo = __shfl(z, 48 + cidx);
            if (t < 16) {
                float fg = sigmoid_fast(zf + 1.0f);   // FORGET_BIAS = 1.0
                float ig = sigmoid_fast(zi);
                float og = sigmoid_fast(zo);
                c_state = c_state * fg + ig * tanh_fast(zj);
                float h = tanh_fast(c_state) * og;
                // pack: round h to 24-bit mantissa, tag in low 8 bits; 16 lanes
                // publish one contiguous 64B line per WG
                unsigned hb  = (__float_as_uint(h) + 0x80u) & 0xFFFFFF00u;
                unsigned pkt = hb | (unsigned)((s + 1) & 255);
                __hip_atomic_store(hslot + (((s + 1) & 1) << 10) + g * 16 + t, pkt,
                                   __ATOMIC_RELAXED, __HIP_MEMORY_SCOPE_AGENT);
                out[(size_t)s * HD + g * 16 + t] = h;  // off critical path
            }
        }
    }
}

// ---------------- launch ----------------
extern "C" void kernel_launch(void* const* d_in, const int* in_sizes, int n_in,
                              void* d_out, int out_size, void* d_ws, size_t ws_size,
                              hipStream_t stream) {
    const float* x = (const float*)d_in[0];   // [8192,1024]
    const float* W = (const float*)d_in[1];   // [2048,4096]
    const float* b = (const float*)d_in[2];   // [4096]
    float* out = (float*)d_out;               // [8192,1024]

    char* ws = (char*)d_ws;
    // ws layout: zx 128MB | hslot 16KB region (8KB used) | Wt/Whp 8MB (time-shared)
    float*          zxp   = (float*)ws;
    const size_t    ZXB   = (size_t)T_STEPS * ZD * sizeof(float);   // 134217728
    unsigned*       hslot = (unsigned*)(ws + ZXB);
    unsigned short* Wt    = (unsigned short*)(ws + ZXB + 16384);
    unsigned*       Whp   = (unsigned*)(ws + ZXB + 16384);          // reuses Wt region

    // h_0 = 0 with tag 0 in both parity slots (ws is poisoned each call)
    hipMemsetAsync(hslot, 0, 8192, stream);

    // phase 0: pack Wx -> bf16 tiles
    wt_pack<<<dim3((IN_DIM * ZD) / 256), dim3(256), 0, stream>>>(W, Wt);

    // phase 1: ZX = x @ Wx + b
    zx_gemm<<<dim3(ZD / BN, T_STEPS / BM), dim3(256), 0, stream>>>(x, Wt, b, zxp);

    // phase 0b: pack Wh -> fp16 pairs into the now-dead Wt region (stream-ordered)
    whp_pack<<<dim3(128), dim3(256), 0, stream>>>(W, Whp);

    // phase 2: sequential recurrence (cooperative for guaranteed co-residency)
    void* args[] = { (void*)&Whp, (void*)&zxp, (void*)&out, (void*)&hslot };
    hipLaunchCooperativeKernel((void*)lstm_seq, dim3(G2), dim3(B2), args, 0, stream);
}

// Round 13
// 12669.971 us; speedup vs baseline: 1.1797x; 1.0008x over previous
//
#include <hip/hip_runtime.h>
#include <hip/hip_fp16.h>
#include <math.h>

// ---------------- constants ----------------
#define T_STEPS 8192
#define IN_DIM  1024
#define HD      1024
#define ZD      4096          // 4 gates * HD, order [i, j, f, o]
#define G2      64            // phase-2 workgroups (each owns 16 h-cols x 4 gates)
#define B2      512           // phase-2 block size (8 waves)

typedef short  short8 __attribute__((ext_vector_type(8)));
typedef float  f32x4  __attribute__((ext_vector_type(4)));
typedef unsigned uint4v __attribute__((ext_vector_type(4)));
typedef _Float16 h2v __attribute__((ext_vector_type(2)));

__device__ __forceinline__ unsigned short f2bf(float f) {
    unsigned u = __float_as_uint(f);
    unsigned r = (u + 0x7fffu + ((u >> 16) & 1u)) >> 16;
    return (unsigned short)r;
}

// pack 2 fp32 -> 2 fp16 (RTZ) as a dword; bit_cast bridges __fp16 vs _Float16 types
__device__ __forceinline__ unsigned pk16(float a, float b) {
    return __builtin_bit_cast(unsigned, __builtin_amdgcn_cvt_pkrtz(a, b));
}

// ---------------- phase 0: pack Wx (rows 0..1023 of W) into bf16 tile layout ----
__global__ void wt_pack(const float* __restrict__ W, unsigned short* __restrict__ Wt) {
    int idx = blockIdx.x * 256 + threadIdx.x;      // 0 .. 4M-1
    int k = idx >> 12;                             // 0..1023
    int c = idx & 4095;                            // 0..4095
    float v = W[(size_t)k * ZD + c];               // coalesced read
    int tn = c >> 7, col = c & 127;
    int tk = k >> 5, kk = k & 31;
    Wt[(((size_t)(tn * 32 + tk) * 128 + col) << 5) + kk] = f2bf(v);
}

// ---------------- phase 0b: pack Wh (rows 1024..2047) into fp16 per-thread runs --
__global__ void whp_pack(const float* __restrict__ W, unsigned* __restrict__ Whp) {
    int i = blockIdx.x * 256 + threadIdx.x;   // 0..32767
    int zcol = i & 4095;
    int seg  = i >> 12;                       // 0..7
    const float* src = W + (size_t)(IN_DIM + (seg << 7)) * ZD + zcol; // lane-coalesced
    unsigned* dst = Whp + ((size_t)zcol * 8 + seg) * 64;              // 256B/thread
    for (int j = 0; j < 64; ++j) {
        float v0 = src[(size_t)(2 * j) * ZD];
        float v1 = src[(size_t)(2 * j + 1) * ZD];
        unsigned lo = (unsigned)__half_as_ushort(__float2half(v0));
        unsigned hi = (unsigned)__half_as_ushort(__float2half(v1));
        dst[j] = lo | (hi << 16);
    }
}

// ---------------- phase 1: ZX = x @ Wx + b (bf16 MFMA, fp32 accum) --------------
#define BM 128
#define BN 128
#define BKK 32
#define LDA 40    // padded LDS stride (bf16 elems)

__global__ __launch_bounds__(256) void zx_gemm(const float* __restrict__ x,
                                               const unsigned short* __restrict__ Wt,
                                               const float* __restrict__ b,
                                               float* __restrict__ zx) {
    __shared__ unsigned short As[128 * LDA];
    __shared__ unsigned short Bs[128 * LDA];
    const int tid  = threadIdx.x;
    const int wave = tid >> 6, lane = tid & 63;
    const int wr = wave & 1, wc = wave >> 1;
    const int m0 = blockIdx.y * BM, n0 = blockIdx.x * BN;
    const int quad = lane >> 4, l16 = lane & 15;

    f32x4 acc[4][4] = {};
    float bias[4];
#pragma unroll
    for (int j = 0; j < 4; ++j) bias[j] = b[n0 + wc * 64 + j * 16 + l16];

    for (int it = 0; it < IN_DIM / BKK; ++it) {
        const int k0 = it * BKK;
        // stage A: x[m0..+127][k0..+31] fp32 -> bf16 LDS
        {
            int r  = tid >> 3;          // 0..31
            int k4 = (tid & 7) * 4;
#pragma unroll
            for (int p = 0; p < 4; ++p) {
                int rr = r + p * 32;
                float4 v = *(const float4*)&x[(size_t)(m0 + rr) * IN_DIM + k0 + k4];
                unsigned p0 = (unsigned)f2bf(v.x) | ((unsigned)f2bf(v.y) << 16);
                unsigned p1 = (unsigned)f2bf(v.z) | ((unsigned)f2bf(v.w) << 16);
                *(uint2*)&As[rr * LDA + k4] = make_uint2(p0, p1);
            }
        }
        // stage B: pre-packed contiguous 8KB tile -> LDS (pad stride 40)
        {
            const uint4* src = (const uint4*)(Wt + ((size_t)(n0 >> 7) * 32 + it) * 4096);
#pragma unroll
            for (int p = 0; p < 2; ++p) {
                int id = tid * 2 + p;           // 0..511
                int col = id >> 2, kp = id & 3;
                uint4 v = src[id];
                *(uint4*)&Bs[col * LDA + kp * 8] = v;
            }
        }
        __syncthreads();
        short8 af[4], bfr[4];
#pragma unroll
        for (int i = 0; i < 4; ++i)
            af[i] = *(const short8*)&As[(wr * 64 + i * 16 + l16) * LDA + quad * 8];
#pragma unroll
        for (int j = 0; j < 4; ++j)
            bfr[j] = *(const short8*)&Bs[(wc * 64 + j * 16 + l16) * LDA + quad * 8];
#pragma unroll
        for (int i = 0; i < 4; ++i)
#pragma unroll
            for (int j = 0; j < 4; ++j)
                acc[i][j] = __builtin_amdgcn_mfma_f32_16x16x32_bf16(af[i], bfr[j], acc[i][j], 0, 0, 0);
        __syncthreads();
    }
    // epilogue: D row = quad*4 + reg, col = l16
#pragma unroll
    for (int i = 0; i < 4; ++i) {
        int row = m0 + wr * 64 + i * 16 + quad * 4;
#pragma unroll
        for (int j = 0; j < 4; ++j) {
            int col = n0 + wc * 64 + j * 16 + l16;
#pragma unroll
            for (int r = 0; r < 4; ++r)
                zx[(size_t)(row + r) * ZD + col] = acc[i][j][r] + bias[j];
        }
    }
}

// ---------------- fast activations (critical path) ----------------
__device__ __forceinline__ float sigmoid_fast(float x) {
    float e = __expf(-x);
    return __builtin_amdgcn_rcpf(1.f + e);
}
__device__ __forceinline__ float tanh_fast(float x) {
    // 1 - 2/(e^{2x}+1); e=inf -> 1, e=0 -> -1 (no NaN at extremes)
    float e = __expf(2.f * x);
    return 1.f - 2.f * __builtin_amdgcn_rcpf(e + 1.f);
}

// ---------------- phase 2: sequential recurrence (cooperative, 64 WGs) ----------
// Base = round-5 PASSING kernel (11.96ms, session best). ONE change:
// s_sleep(2) (~128cy) backoff after a FAILED tag check, before re-polling.
// Rationale: 16384 lanes continuously re-poll the same 64 hot LLC lines at max
// rate; redundant polls occupy the LLC banks that publish stores must win
// arbitration against. r4->r5's poll-request halving was worth -0.44us/step
// (partially confounded with dot2). Backoff cuts redundant polls with ZERO cost
// on the ready path (first check is immediate) and bounded cost on the miss path
// (sampling interval ~600->~730cy, expected +65cy detect delay).
// Falsifier: neutral result => congestion ruled out, step is at its latency floor.
// Wave-autonomous rewrite (r11/r12) abandoned: deterministic wrong-answer bug
// not localizable in two rounds; do not retry without a local repro harness.
__global__ __launch_bounds__(B2, 2) void lstm_seq(const unsigned* __restrict__ whp,
                                                  const float* __restrict__ zx,
                                                  float* __restrict__ out,
                                                  unsigned* hslot) {
    __shared__ unsigned lds_hh[512];       // fp16-packed h: dword d = {h[2d], h[2d+1]}
    __shared__ float pbuf[2][B2];
    __shared__ float zx_lds[2][64];
    const int g    = blockIdx.x;
    const int t    = threadIdx.x;
    const int seg  = t >> 6;           // 0..7 == wave index
    const int lane = t & 63;
    const int gate = lane >> 4;        // 0..3  [i,j,f,o]
    const int cidx = lane & 15;
    const int zcol = g * 16 + cidx + (gate << 10);

    // Wh slice -> 64 packed-fp16 dwords (compiler-managed; pinning proved harmful
    // or neutral in r1/r3/r10 — the stream latency hides under the spin)
    unsigned wp[64];
    {
        const unsigned* wsrc = whp + ((size_t)zcol * 8 + seg) * 64;
#pragma unroll
        for (int j = 0; j < 64; ++j) wp[j] = wsrc[j];
    }

    // preload zx row 0 (wave 1); consumed in phase C of step 0
    if (t >= 64 && t < 128) {
        int l = t - 64;
        zx_lds[0][l] = zx[(size_t)0 * ZD + (size_t)(l >> 4) * 1024 + g * 16 + (l & 15)];
    }
    __syncthreads();   // cover zx_lds[0] for step-0 C-phase (outside the loop)

    float c_state = 0.f;

    for (int s = 0; s < T_STEPS; ++s) {
        const int par = s & 1;
        // wave 1: issue zx prefetch for step s+1 BEFORE the spin (overlaps the
        // poll's vmcnt(0) wait — max, not sum; r7 proved moving it later hurts)
        float znext = 0.f;
        if (t >= 64 && t < 128 && s + 1 < T_STEPS) {
            int l = t - 64;
            znext = zx[(size_t)(s + 1) * ZD + (size_t)(l >> 4) * 1024 + g * 16 + (l & 15)];
        }
        // ---- A: acquire own slice — lanes 0..31 poll 16B = 4 tagged packets ----
        if (lane < 32) {
            const unsigned want = (unsigned)(s & 255);
            const unsigned* ap = hslot + (par << 10) + (seg << 7) + (lane << 2);
            uint4v pv;
            for (;;) {
                asm volatile("global_load_dwordx4 %0, %1, off sc0 sc1\n\t"
                             "s_waitcnt vmcnt(0)"
                             : "=v"(pv) : "v"(ap) : "memory");
                unsigned bad = ((pv.x ^ want) | (pv.y ^ want) |
                                (pv.z ^ want) | (pv.w ^ want)) & 255u;
                if (bad == 0) break;
                __builtin_amdgcn_s_sleep(2);   // ~128cy backoff: decongest hslot
            }
            // convert 4 fp32 packets -> 2 packed-fp16 dwords (tag bits sub-ulp)
            unsigned d0 = pk16(__uint_as_float(pv.x), __uint_as_float(pv.y));
            unsigned d1 = pk16(__uint_as_float(pv.z), __uint_as_float(pv.w));
            *(uint2*)&lds_hh[(seg << 6) + 2 * lane] = make_uint2(d0, d1);
        }
        // ---- B: 64 dot2 against fp16 weights (own slice) ----
        float a0 = 0.f, a1 = 0.f, a2 = 0.f, a3 = 0.f;
        const uint4* hp = (const uint4*)&lds_hh[seg << 6];
#pragma unroll
        for (int j = 0; j < 16; ++j) {
            uint4 hv = hp[j];    // same addr across wave: LDS broadcast, no conflict
            a0 = __builtin_amdgcn_fdot2(__builtin_bit_cast(h2v, wp[4 * j + 0]),
                                        __builtin_bit_cast(h2v, hv.x), a0, false);
            a1 = __builtin_amdgcn_fdot2(__builtin_bit_cast(h2v, wp[4 * j + 1]),
                                        __builtin_bit_cast(h2v, hv.y), a1, false);
            a2 = __builtin_amdgcn_fdot2(__builtin_bit_cast(h2v, wp[4 * j + 2]),
                                        __builtin_bit_cast(h2v, hv.z), a2, false);
            a3 = __builtin_amdgcn_fdot2(__builtin_bit_cast(h2v, wp[4 * j + 3]),
                                        __builtin_bit_cast(h2v, hv.w), a3, false);
        }
        pbuf[par][t] = (a0 + a1) + (a2 + a3);
        if (t >= 64 && t < 128)                  // park prefetched zx for next step
            zx_lds[(s + 1) & 1][t - 64] = znext;
        __syncthreads();                         // the ONLY barrier per step
        // ---- C: wave 0 reduces, gates, publishes ----
        if (t < 64) {
            float z = zx_lds[s & 1][t];
#pragma unroll
            for (int ss = 0; ss < 8; ++ss) z += pbuf[par][(ss << 6) + t];
            float zi = __shfl(z, cidx);
            float zj = __shfl(z, 16 + cidx);
            float zf = __shfl(z, 32 + cidx);
            float zo = __shfl(z, 48 + cidx);
            if (t < 16) {
                float fg = sigmoid_fast(zf + 1.0f);   // FORGET_BIAS = 1.0
                float ig = sigmoid_fast(zi);
                float og = sigmoid_fast(zo);
                c_state = c_state * fg + ig * tanh_fast(zj);
                float h = tanh_fast(c_state) * og;
                // pack: round h to 24-bit mantissa, tag in low 8 bits; 16 lanes
                // publish one contiguous 64B line per WG
                unsigned hb  = (__float_as_uint(h) + 0x80u) & 0xFFFFFF00u;
                unsigned pkt = hb | (unsigned)((s + 1) & 255);
                __hip_atomic_store(hslot + (((s + 1) & 1) << 10) + g * 16 + t, pkt,
                                   __ATOMIC_RELAXED, __HIP_MEMORY_SCOPE_AGENT);
                out[(size_t)s * HD + g * 16 + t] = h;  // off critical path
            }
        }
    }
}

// ---------------- launch ----------------
extern "C" void kernel_launch(void* const* d_in, const int* in_sizes, int n_in,
                              void* d_out, int out_size, void* d_ws, size_t ws_size,
                              hipStream_t stream) {
    const float* x = (const float*)d_in[0];   // [8192,1024]
    const float* W = (const float*)d_in[1];   // [2048,4096]
    const float* b = (const float*)d_in[2];   // [4096]
    float* out = (float*)d_out;               // [8192,1024]

    char* ws = (char*)d_ws;
    // ws layout: zx 128MB | hslot 16KB region (8KB used) | Wt/Whp 8MB (time-shared)
    float*          zxp   = (float*)ws;
    const size_t    ZXB   = (size_t)T_STEPS * ZD * sizeof(float);   // 134217728
    unsigned*       hslot = (unsigned*)(ws + ZXB);
    unsigned short* Wt    = (unsigned short*)(ws + ZXB + 16384);
    unsigned*       Whp   = (unsigned*)(ws + ZXB + 16384);          // reuses Wt region

    // h_0 = 0 with tag 0 in both parity slots (ws is poisoned each call)
    hipMemsetAsync(hslot, 0, 8192, stream);

    // phase 0: pack Wx -> bf16 tiles
    wt_pack<<<dim3((IN_DIM * ZD) / 256), dim3(256), 0, stream>>>(W, Wt);

    // phase 1: ZX = x @ Wx + b
    zx_gemm<<<dim3(ZD / BN, T_STEPS / BM), dim3(256), 0, stream>>>(x, Wt, b, zxp);

    // phase 0b: pack Wh -> fp16 pairs into the now-dead Wt region (stream-ordered)
    whp_pack<<<dim3(128), dim3(256), 0, stream>>>(W, Whp);

    // phase 2: sequential recurrence (cooperative for guaranteed co-residency)
    void* args[] = { (void*)&Whp, (void*)&zxp, (void*)&out, (void*)&hslot };
    hipLaunchCooperativeKernel((void*)lstm_seq, dim3(G2), dim3(B2), args, 0, stream);
}